// Round 2
// baseline (2565.329 us; speedup 1.0000x reference)
//
#include <hip/hip_runtime.h>
#include <math.h>

#define B_ 16
#define C_ 512
#define Nn 3136
#define HEADS 8
#define HD 64
#define AG 49
#define Mrows (B_ * Nn)   // 50176

typedef unsigned short ushortT;

__device__ inline float bf2f(ushortT u) { return __uint_as_float(((unsigned)u) << 16); }
__device__ inline ushortT f2bf(float f) {
    unsigned x = __float_as_uint(f);
    unsigned r = (x + 0x7fffu + ((x >> 16) & 1u)) >> 16;   // round-nearest-even
    return (ushortT)r;
}

// ---- overloaded 4-elem load (to fp32) / store (from fp32) ----
__device__ inline float4 load4(const float* p) { return *(const float4*)p; }
__device__ inline float4 load4(const ushortT* p) {
    ushort4 u = *(const ushort4*)p;
    return make_float4(bf2f(u.x), bf2f(u.y), bf2f(u.z), bf2f(u.w));
}
__device__ inline void store4(float* p, float4 o) { *(float4*)p = o; }
__device__ inline void store4(ushortT* p, float4 o) {
    ushort4 s = make_ushort4(f2bf(o.x), f2bf(o.y), f2bf(o.z), f2bf(o.w));
    *(ushort4*)p = s;
}

// ---------------- tiled fp32 GEMM: out[m,n] = sum_k A[m,k] * W[n,k] (+bias[n]) ----------
// W cols [0,split) from W0, [split,N) from W1 (row n-split). split % 64 == 0.
template <typename TA, typename TO>
__global__ __launch_bounds__(256)
void gemm_bt(const TA* __restrict__ A, const float* __restrict__ W0,
             const float* __restrict__ W1, int split,
             const float* __restrict__ bias,
             TO* __restrict__ out, int M, int N, int K) {
    __shared__ float As[16][64];
    __shared__ float Bs[16][64];
    int t  = threadIdx.x;
    int tx = t & 15, ty = t >> 4;
    int m0 = blockIdx.y * 64;
    int n0 = blockIdx.x * 64;
    const float* Wp;
    int nc0;
    if (n0 < split) { Wp = W0; nc0 = n0; } else { Wp = W1; nc0 = n0 - split; }
    float acc[4][4] = {};
    int lm = t >> 2;          // 0..63
    int lk = (t & 3) << 2;    // 0,4,8,12
    for (int k0 = 0; k0 < K; k0 += 16) {
        float4 avv = load4(&A [(size_t)(m0  + lm) * K + k0 + lk]);
        float4 bvv = load4(&Wp[(size_t)(nc0 + lm) * K + k0 + lk]);
        As[lk + 0][lm] = avv.x; As[lk + 1][lm] = avv.y;
        As[lk + 2][lm] = avv.z; As[lk + 3][lm] = avv.w;
        Bs[lk + 0][lm] = bvv.x; Bs[lk + 1][lm] = bvv.y;
        Bs[lk + 2][lm] = bvv.z; Bs[lk + 3][lm] = bvv.w;
        __syncthreads();
#pragma unroll
        for (int kk = 0; kk < 16; ++kk) {
            float4 a4 = *(const float4*)&As[kk][ty << 2];
            float4 b4 = *(const float4*)&Bs[kk][tx << 2];
            float ar[4] = {a4.x, a4.y, a4.z, a4.w};
            float br[4] = {b4.x, b4.y, b4.z, b4.w};
#pragma unroll
            for (int i = 0; i < 4; ++i)
#pragma unroll
                for (int j = 0; j < 4; ++j) acc[i][j] += ar[i] * br[j];
        }
        __syncthreads();
    }
#pragma unroll
    for (int i = 0; i < 4; ++i) {
        int m = m0 + (ty << 2) + i;
        int n = n0 + (tx << 2);
        float4 o = make_float4(acc[i][0], acc[i][1], acc[i][2], acc[i][3]);
        if (bias) { o.x += bias[n]; o.y += bias[n + 1]; o.z += bias[n + 2]; o.w += bias[n + 3]; }
        store4(&out[(size_t)m * N + n], o);
    }
}

// ---------------- agent tokens: 8x8 mean pool of q (bf16 in, fp32 out) ----------------
__global__ void agent_pool(const ushortT* __restrict__ qkv, float* __restrict__ at) {
    int g = blockIdx.x * 256 + threadIdx.x;       // B*49*512
    if (g >= B_ * AG * C_) return;
    int c = g & 511;
    int a = (g >> 9) % AG;
    int b = g / (AG * C_);
    int p1 = a / 7, p2 = a % 7;
    float s = 0.f;
#pragma unroll
    for (int yy = 0; yy < 8; ++yy)
#pragma unroll
        for (int xx = 0; xx < 8; ++xx) {
            int i = (p1 * 8 + yy) * 56 + (p2 * 8 + xx);
            s += bf2f(qkv[(size_t)(b * Nn + i) * 1536 + c]);
        }
    at[g] = s * (1.f / 64.f);
}

// ---------------- bilinear 7->56 (half-pixel centers, clamped == jax edge norm) --------
__device__ inline float bilin7(const float* __restrict__ p, int y, int x) {
    float fy = fminf(fmaxf(y * 0.125f - 0.4375f, 0.f), 6.f);
    float fx = fminf(fmaxf(x * 0.125f - 0.4375f, 0.f), 6.f);
    int y0 = (int)fy; float ty = fy - y0; int y1 = min(y0 + 1, 6);
    int x0 = (int)fx; float tx = fx - x0; int x1 = min(x0 + 1, 6);
    float v00 = p[y0 * 7 + x0], v01 = p[y0 * 7 + x1];
    float v10 = p[y1 * 7 + x0], v11 = p[y1 * 7 + x1];
    return (1.f - ty) * ((1.f - tx) * v00 + tx * v01) + ty * ((1.f - tx) * v10 + tx * v11);
}

__global__ void bias1_k(const float* __restrict__ an, const float* __restrict__ ahb,
                        const float* __restrict__ awb, float* __restrict__ out) {
    int g = blockIdx.x * 256 + threadIdx.x;       // [h][a][i]
    if (g >= HEADS * AG * Nn) return;
    int i = g % Nn; int a = (g / Nn) % AG; int h = g / (AG * Nn);
    int y = i / 56, x = i % 56;
    float v = bilin7(an + (h * AG + a) * 49, y, x);
    out[g] = v + ahb[(h * AG + a) * 56 + y] + awb[(h * AG + a) * 56 + x];
}

__global__ void bias2_k(const float* __restrict__ na, const float* __restrict__ hab,
                        const float* __restrict__ wab, float* __restrict__ out) {
    int g = blockIdx.x * 256 + threadIdx.x;       // [h][i][a]
    if (g >= HEADS * Nn * AG) return;
    int a = g % AG; int i = (g / AG) % Nn; int h = g / (AG * Nn);
    int y = i / 56, x = i % 56;
    float v = bilin7(na + (h * AG + a) * 49, y, x);
    out[g] = v + hab[(h * 56 + y) * AG + a] + wab[(h * 56 + x) * AG + a];
}

// ---------------- agent logits: L[bh][a][i] = scale*ah.k + bias1 (bf16 out) ------------
__global__ __launch_bounds__(256)
void agent_logits_k(const ushortT* __restrict__ qkv, const float* __restrict__ at,
                    const float* __restrict__ b1, ushortT* __restrict__ L) {
    __shared__ float ah_s[AG][HD];
    __shared__ float k_s[64][HD + 1];
    int bh = blockIdx.y;                  // 0..127
    int b = bh >> 3, h = bh & 7;
    int i0 = blockIdx.x * 64;
    int t = threadIdx.x;
    for (int idx = t; idx < AG * HD; idx += 256) {
        int a = idx >> 6, d = idx & 63;
        ah_s[a][d] = at[((b * AG + a) << 9) + (h << 6) + d] * 0.125f;
    }
    for (int idx = t; idx < 64 * HD; idx += 256) {
        int i = idx >> 6, d = idx & 63;
        k_s[i][d] = bf2f(qkv[(size_t)(b * Nn + i0 + i) * 1536 + 512 + (h << 6) + d]);
    }
    __syncthreads();
    int il = t & 63;
    int ab = t >> 6;
    for (int a = ab; a < AG; a += 4) {
        float acc = 0.f;
#pragma unroll 16
        for (int d = 0; d < 64; ++d) acc += ah_s[a][d] * k_s[il][d];
        L[(size_t)(bh * AG + a) * Nn + i0 + il] =
            f2bf(acc + b1[(h * AG + a) * Nn + i0 + il]);
    }
}

// ---------------- softmax over bf16 rows of length Nn (exp staged in LDS) --------------
__global__ __launch_bounds__(256)
void softmax_rows_bf(ushortT* __restrict__ L) {
    __shared__ float ex[Nn];
    __shared__ float red[256];
    ushortT* p = L + (size_t)blockIdx.x * Nn;
    int t = threadIdx.x;
    float m = -1e30f;
    for (int i = t; i < Nn; i += 256) { float v = bf2f(p[i]); ex[i] = v; m = fmaxf(m, v); }
    red[t] = m; __syncthreads();
    for (int s = 128; s; s >>= 1) { if (t < s) red[t] = fmaxf(red[t], red[t + s]); __syncthreads(); }
    m = red[0]; __syncthreads();
    float sum = 0.f;
    for (int i = t; i < Nn; i += 256) { float e = __expf(ex[i] - m); ex[i] = e; sum += e; }
    red[t] = sum; __syncthreads();
    for (int s = 128; s; s >>= 1) { if (t < s) red[t] += red[t + s]; __syncthreads(); }
    float inv = 1.f / red[0];
    for (int i = t; i < Nn; i += 256) p[i] = f2bf(ex[i] * inv);
}

__global__ void zerof(float* __restrict__ p, int nfl) {
    int g = blockIdx.x * 256 + threadIdx.x;
    if (g < nfl) p[g] = 0.f;
}

// ---------------- agent_v[bh][a][d] = sum_i P[a,i] v[i,d]  (split-K, fp32 atomics) -----
__global__ __launch_bounds__(256)
void agent_v_k(const ushortT* __restrict__ qkv, const ushortT* __restrict__ L,
               float* __restrict__ av) {
    __shared__ float P_s[AG][64];
    __shared__ float v_s[64][HD];
    int bh = blockIdx.y; int b = bh >> 3, h = bh & 7;
    int chunk = blockIdx.x;               // 0..6
    int t = threadIdx.x;
    int dl = t & 63, ab = t >> 6;
    float acc[13] = {};
    for (int sub = 0; sub < 7; ++sub) {
        int i0 = chunk * 448 + sub * 64;
        for (int idx = t; idx < AG * 64; idx += 256) {
            int a = idx >> 6, il = idx & 63;
            P_s[a][il] = bf2f(L[(size_t)(bh * AG + a) * Nn + i0 + il]);
        }
        for (int idx = t; idx < 64 * HD; idx += 256) {
            int i = idx >> 6, d = idx & 63;
            v_s[i][d] = bf2f(qkv[(size_t)(b * Nn + i0 + i) * 1536 + 1024 + (h << 6) + d]);
        }
        __syncthreads();
        int j = 0;
        for (int a = ab; a < AG; a += 4, ++j) {
            float s = 0.f;
#pragma unroll 16
            for (int i = 0; i < 64; ++i) s += P_s[a][i] * v_s[i][dl];
            acc[j] += s;
        }
        __syncthreads();
    }
    int j = 0;
    for (int a = ab; a < AG; a += 4, ++j)
        atomicAdd(&av[((bh * AG + a) << 6) + dl], acc[j]);
}

// ---------------- fused q-attention: logits(49) -> softmax -> blend agent_v ------------
__global__ __launch_bounds__(256)
void q_attn_k(const ushortT* __restrict__ qkv, const float* __restrict__ at,
              const float* __restrict__ av, const float* __restrict__ b2,
              ushortT* __restrict__ attn) {
    __shared__ float ah_s[AG][65];
    __shared__ float av_s[AG][65];
    __shared__ float q_s[4][64];
    __shared__ float p_s[4][64];
    int bh = blockIdx.y; int b = bh >> 3, h = bh & 7;
    int i0 = blockIdx.x * 64;
    int t = threadIdx.x;
    int lane = t & 63, wv = t >> 6;
    for (int idx = t; idx < AG * 64; idx += 256) {
        int a = idx >> 6, d = idx & 63;
        ah_s[a][d] = at[((b * AG + a) << 9) + (h << 6) + d];
        av_s[a][d] = av[((bh * AG + a) << 6) + d];
    }
    __syncthreads();
    for (int r = 0; r < 16; ++r) {
        int i = i0 + (wv << 4) + r;
        q_s[wv][lane] = bf2f(qkv[(size_t)(b * Nn + i) * 1536 + (h << 6) + lane]) * 0.125f;
        __syncthreads();
        float lg = -1e30f;
        int a = lane;
        if (a < AG) {
            float s = 0.f;
#pragma unroll 16
            for (int d = 0; d < 64; ++d) s += q_s[wv][d] * ah_s[a][d];
            lg = s + b2[((size_t)h * Nn + i) * AG + a];
        }
        float mx = lg;
#pragma unroll
        for (int off = 32; off; off >>= 1) mx = fmaxf(mx, __shfl_xor(mx, off));
        float e = (a < AG) ? __expf(lg - mx) : 0.f;
        float sm = e;
#pragma unroll
        for (int off = 32; off; off >>= 1) sm += __shfl_xor(sm, off);
        if (a < AG) p_s[wv][a] = e / sm;
        __syncthreads();
        float o = 0.f;
#pragma unroll 7
        for (int aa = 0; aa < AG; ++aa) o += p_s[wv][aa] * av_s[aa][lane];
        attn[(size_t)(b * Nn + i) * C_ + (h << 6) + lane] = f2bf(o);
        __syncthreads();
    }
}

// ---------------- depthwise 3x3 conv on v, added into attn (bf16 RMW) ------------------
__global__ void dwc_add_k(const ushortT* __restrict__ qkv, const float* __restrict__ w,
                          const float* __restrict__ bb, ushortT* __restrict__ attn) {
    int g = blockIdx.x * 256 + threadIdx.x;      // B*Nn*C
    int c = g & 511;
    int i = (g >> 9) % Nn;
    int b = g / (Nn * C_);
    int y = i / 56, x = i % 56;
    float acc = bb[c];
#pragma unroll
    for (int dy = -1; dy <= 1; ++dy) {
        int yy = y + dy;
        if (yy < 0 || yy > 55) continue;
#pragma unroll
        for (int dx = -1; dx <= 1; ++dx) {
            int xx = x + dx;
            if (xx < 0 || xx > 55) continue;
            acc += bf2f(qkv[(size_t)(b * Nn + yy * 56 + xx) * 1536 + 1024 + c])
                   * w[c * 9 + (dy + 1) * 3 + (dx + 1)];
        }
    }
    attn[g] = f2bf(bf2f(attn[g]) + acc);
}

extern "C" void kernel_launch(void* const* d_in, const int* in_sizes, int n_in,
                              void* d_out, int out_size, void* d_ws, size_t ws_size,
                              hipStream_t stream) {
    const float* x      = (const float*)d_in[0];
    const float* q_w    = (const float*)d_in[3];
    const float* kv_w   = (const float*)d_in[4];
    const float* proj_w = (const float*)d_in[5];
    const float* proj_b = (const float*)d_in[6];
    const float* dwc_w  = (const float*)d_in[7];
    const float* dwc_b  = (const float*)d_in[8];
    const float* an_b   = (const float*)d_in[9];
    const float* na_b   = (const float*)d_in[10];
    const float* ah_b   = (const float*)d_in[11];
    const float* aw_b   = (const float*)d_in[12];
    const float* ha_b   = (const float*)d_in[13];
    const float* wa_b   = (const float*)d_in[14];
    float* out = (float*)d_out;

    // ---- workspace layout (bytes), total 218,566,656 B ≈ 208.4 MiB ----
    char* ws = (char*)d_ws;
    ushortT* qkv  = (ushortT*)(ws);                 // 50176*1536 bf16 = 154,140,672
    ushortT* attn = (ushortT*)(ws + 154140672);     // 50176*512  bf16 =  51,380,224
    float*   at   = (float*)(ws + 205520896);       // 16*49*512  f32  =   1,605,632
    float*   b1   = (float*)(ws + 207126528);       // 8*49*3136  f32  =   4,917,248
    float*   b2   = (float*)(ws + 212043776);       // 8*3136*49  f32  =   4,917,248
    float*   av   = (float*)(ws + 216961024);       // 128*49*64  f32  =   1,605,632
    ushortT* L    = attn;   // overlay: L (6272*3136 bf16 = 39.3 MB) dead before attn written

    // 1) fused QKV GEMM: qkv = x @ [q_w; kv_w]^T  (fp32 in, bf16 out)
    gemm_bt<float, ushortT><<<dim3(24, 784), 256, 0, stream>>>(
        x, q_w, kv_w, 512, nullptr, qkv, Mrows, 1536, 512);
    // 2) agent tokens (8x8 mean pool of q)
    agent_pool<<<1568, 256, 0, stream>>>(qkv, at);
    // 3) position biases
    bias1_k<<<4802, 256, 0, stream>>>(an_b, ah_b, aw_b, b1);
    bias2_k<<<4802, 256, 0, stream>>>(na_b, ha_b, wa_b, b2);
    // 4) agent attention: logits -> softmax -> P @ V
    agent_logits_k<<<dim3(49, 128), 256, 0, stream>>>(qkv, at, b1, L);
    softmax_rows_bf<<<6272, 256, 0, stream>>>(L);
    zerof<<<1568, 256, 0, stream>>>(av, B_ * HEADS * AG * HD);
    agent_v_k<<<dim3(7, 128), 256, 0, stream>>>(qkv, L, av);
    // 5) q attention fused
    q_attn_k<<<dim3(49, 128), 256, 0, stream>>>(qkv, at, av, b2, attn);
    // 6) depthwise conv add
    dwc_add_k<<<100352, 256, 0, stream>>>(qkv, dwc_w, dwc_b, attn);
    // 7) output projection (bf16 in, fp32 out)
    gemm_bt<ushortT, float><<<dim3(8, 784), 256, 0, stream>>>(
        attn, proj_w, proj_w, 512, proj_b, out, Mrows, 512, 512);
}

// Round 3
// 722.952 us; speedup vs baseline: 3.5484x; 3.5484x over previous
//
#include <hip/hip_runtime.h>
#include <math.h>

#define B_ 16
#define C_ 512
#define Nn 3136
#define HEADS 8
#define HD 64
#define AG 49
#define Mrows (B_ * Nn)   // 50176

typedef unsigned short ushortT;
typedef __attribute__((ext_vector_type(8))) short bf16x8;
typedef __attribute__((ext_vector_type(4))) float f32x4;

#define MFMA16(a, b, c) __builtin_amdgcn_mfma_f32_16x16x32_bf16((a), (b), (c), 0, 0, 0)

__device__ inline float bf2f(ushortT u) { return __uint_as_float(((unsigned)u) << 16); }
__device__ inline ushortT f2bf(float f) {
    unsigned x = __float_as_uint(f);
    unsigned r = (x + 0x7fffu + ((x >> 16) & 1u)) >> 16;   // RNE
    return (ushortT)r;
}
__device__ inline f32x4 fzero4() { f32x4 z = {0.f, 0.f, 0.f, 0.f}; return z; }

// async global->LDS, 16B per lane; lds dest = wave-uniform base + lane*16
__device__ inline void gl_lds16(const ushortT* g, ushortT* l) {
    __builtin_amdgcn_global_load_lds(
        (const __attribute__((address_space(1))) void*)g,
        (__attribute__((address_space(3))) void*)l, 16, 0, 0);
}

// ============ fp32 -> bf16 elementwise (x, weights) ============
__global__ void cvt_f2b4(const float* __restrict__ src, ushortT* __restrict__ dst, int n4) {
    int g = blockIdx.x * 256 + threadIdx.x;
    if (g >= n4) return;
    float4 v = *(const float4*)&src[(size_t)g * 4];
    ushort4 o = make_ushort4(f2bf(v.x), f2bf(v.y), f2bf(v.z), f2bf(v.w));
    *(ushort4*)&dst[(size_t)g * 4] = o;
}

// dwc_w [c][3][3] -> wT [tap][c] fp32
__global__ void repack_w(const float* __restrict__ w, float* __restrict__ wT) {
    int g = blockIdx.x * 256 + threadIdx.x;
    if (g >= 9 * 512) return;
    int c = g % 512, tap = g / 512;
    wT[g] = w[c * 9 + tap];
}

// ============ MFMA GEMM: out[m,n] = sum_k A[m,k]*Bw[n,k] (+bias), 128x128x32 tiles ======
template <typename TO>
__global__ __launch_bounds__(256)
void gemm_mfma(const ushortT* __restrict__ A, const ushortT* __restrict__ Bw,
               const float* __restrict__ bias, TO* __restrict__ out,
               int N, int K) {
    __shared__ __align__(16) ushortT As[4096];   // chunk c=(kc*128+row) at c*8, 8 bf16 each
    __shared__ __align__(16) ushortT Bs[4096];
    const int t = threadIdx.x, lane = t & 63, wid = t >> 6;
    const int m0 = blockIdx.y * 128, n0 = blockIdx.x * 128;
    const int wm = (wid & 1) << 6, wn = (wid >> 1) << 6;
    f32x4 acc[4][4];
#pragma unroll
    for (int i = 0; i < 4; ++i)
#pragma unroll
        for (int j = 0; j < 4; ++j) acc[i][j] = fzero4();
    const int c0 = wid * 128 + lane, c1 = c0 + 64;
    const int kc0 = c0 >> 7, r0 = c0 & 127;
    const int kc1 = c1 >> 7, r1 = c1 & 127;
    const ushortT* ga0 = A  + (size_t)(m0 + r0) * K + kc0 * 8;
    const ushortT* ga1 = A  + (size_t)(m0 + r1) * K + kc1 * 8;
    const ushortT* gb0 = Bw + (size_t)(n0 + r0) * K + kc0 * 8;
    const ushortT* gb1 = Bw + (size_t)(n0 + r1) * K + kc1 * 8;
    ushortT* lA0 = As + wid * 1024;  ushortT* lA1 = lA0 + 512;
    ushortT* lB0 = Bs + wid * 1024;  ushortT* lB1 = lB0 + 512;
    const int kc = lane >> 4, rr15 = lane & 15;
    for (int k0 = 0; k0 < K; k0 += 32) {
        gl_lds16(ga0 + k0, lA0);
        gl_lds16(ga1 + k0, lA1);
        gl_lds16(gb0 + k0, lB0);
        gl_lds16(gb1 + k0, lB1);
        __syncthreads();
        bf16x8 af[4], bfr[4];
#pragma unroll
        for (int i = 0; i < 4; ++i) {
            af[i]  = *(const bf16x8*)&As[(kc * 128 + wm + i * 16 + rr15) * 8];
            bfr[i] = *(const bf16x8*)&Bs[(kc * 128 + wn + i * 16 + rr15) * 8];
        }
#pragma unroll
        for (int i = 0; i < 4; ++i)
#pragma unroll
            for (int j = 0; j < 4; ++j)
                acc[i][j] = MFMA16(af[i], bfr[j], acc[i][j]);
        __syncthreads();
    }
    const int cn = lane & 15, rg = (lane >> 4) << 2;
#pragma unroll
    for (int i = 0; i < 4; ++i) {
        int mrow = m0 + wm + i * 16 + rg;
#pragma unroll
        for (int j = 0; j < 4; ++j) {
            int ncol = n0 + wn + j * 16 + cn;
            float bv = bias ? bias[ncol] : 0.f;
#pragma unroll
            for (int r = 0; r < 4; ++r) {
                float v = acc[i][j][r] + bv;
                if (sizeof(TO) == 2) ((ushortT*)out)[(size_t)(mrow + r) * N + ncol] = f2bf(v);
                else                 ((float*)out)[(size_t)(mrow + r) * N + ncol] = v;
            }
        }
    }
}

// ============ agent tokens: 8x8 mean pool of q (bf16 in, fp32 out), 8ch/thread ==========
__global__ void agent_pool(const ushortT* __restrict__ qkv, float* __restrict__ at) {
    int g = blockIdx.x * 256 + threadIdx.x;       // 16*49*64
    int c8 = (g & 63) << 3;
    int a = (g >> 6) % AG;
    int b = g / (AG * 64);
    int p1 = a / 7, p2 = a % 7;
    float s[8] = {};
    for (int yy = 0; yy < 8; ++yy)
#pragma unroll
        for (int xx = 0; xx < 8; ++xx) {
            int i = (p1 * 8 + yy) * 56 + (p2 * 8 + xx);
            const ushortT* p = &qkv[(size_t)(b * Nn + i) * 1536 + c8];
            ushort4 u0 = *(const ushort4*)p;
            ushort4 u1 = *(const ushort4*)(p + 4);
            s[0] += bf2f(u0.x); s[1] += bf2f(u0.y); s[2] += bf2f(u0.z); s[3] += bf2f(u0.w);
            s[4] += bf2f(u1.x); s[5] += bf2f(u1.y); s[6] += bf2f(u1.z); s[7] += bf2f(u1.w);
        }
    float* o = &at[((size_t)(b * AG + a) << 9) + c8];
#pragma unroll
    for (int j = 0; j < 8; ++j) o[j] = s[j] * (1.f / 64.f);
}

// ============ bilinear 7->56 biases (unchanged) ============
__device__ inline float bilin7(const float* __restrict__ p, int y, int x) {
    float fy = fminf(fmaxf(y * 0.125f - 0.4375f, 0.f), 6.f);
    float fx = fminf(fmaxf(x * 0.125f - 0.4375f, 0.f), 6.f);
    int y0 = (int)fy; float ty = fy - y0; int y1 = min(y0 + 1, 6);
    int x0 = (int)fx; float tx = fx - x0; int x1 = min(x0 + 1, 6);
    float v00 = p[y0 * 7 + x0], v01 = p[y0 * 7 + x1];
    float v10 = p[y1 * 7 + x0], v11 = p[y1 * 7 + x1];
    return (1.f - ty) * ((1.f - tx) * v00 + tx * v01) + ty * ((1.f - tx) * v10 + tx * v11);
}

__global__ void bias1_k(const float* __restrict__ an, const float* __restrict__ ahb,
                        const float* __restrict__ awb, float* __restrict__ out) {
    int g = blockIdx.x * 256 + threadIdx.x;       // [h][a][i]
    if (g >= HEADS * AG * Nn) return;
    int i = g % Nn; int a = (g / Nn) % AG; int h = g / (AG * Nn);
    int y = i / 56, x = i % 56;
    float v = bilin7(an + (h * AG + a) * 49, y, x);
    out[g] = v + ahb[(h * AG + a) * 56 + y] + awb[(h * AG + a) * 56 + x];
}

__global__ void bias2_k(const float* __restrict__ na, const float* __restrict__ hab,
                        const float* __restrict__ wab, float* __restrict__ out) {
    int g = blockIdx.x * 256 + threadIdx.x;       // [h][i][a]
    if (g >= HEADS * Nn * AG) return;
    int a = g % AG; int i = (g / AG) % Nn; int h = g / (AG * Nn);
    int y = i / 56, x = i % 56;
    float v = bilin7(na + (h * AG + a) * 49, y, x);
    out[g] = v + hab[(h * 56 + y) * AG + a] + wab[(h * 56 + x) * AG + a];
}

// ============ agent logits via MFMA: L[a][i] = (0.125*ah[a])·k[i] + b1 ============
// D[m=a][n=i]: A = ah_s (LDS), B = k rows (direct global frags). grid (7, 128)
__global__ __launch_bounds__(256)
void agent_logits_mfma(const ushortT* __restrict__ qkv, const float* __restrict__ at,
                       const float* __restrict__ b1, ushortT* __restrict__ L) {
    __shared__ __align__(16) ushortT ah_s[64 * 72];
    int t = threadIdx.x, lane = t & 63, wid = t >> 6;
    int bh = blockIdx.y, b = bh >> 3, h = bh & 7;
    for (int idx = t; idx < 512; idx += 256) {
        int a = idx >> 3, d8 = (idx & 7) << 3;
        bf16x8 tmp;
        if (a < AG) {
            const float* p = &at[((size_t)(b * AG + a) << 9) + (h << 6) + d8];
#pragma unroll
            for (int j = 0; j < 8; ++j) tmp[j] = (short)f2bf(p[j] * 0.125f);
        } else {
#pragma unroll
            for (int j = 0; j < 8; ++j) tmp[j] = 0;
        }
        *(bf16x8*)&ah_s[a * 72 + d8] = tmp;
    }
    __syncthreads();
    int r15 = lane & 15, kq = (lane >> 4) << 3;
    bf16x8 af[4][2];
#pragma unroll
    for (int mt = 0; mt < 4; ++mt)
#pragma unroll
        for (int ks = 0; ks < 2; ++ks)
            af[mt][ks] = *(const bf16x8*)&ah_s[(mt * 16 + r15) * 72 + ks * 32 + kq];
    int i0b = blockIdx.x * 448;
    int rbase = (lane >> 4) << 2;
    for (int tt = 0; tt < 7; ++tt) {
        int i0 = i0b + (wid * 7 + tt) * 16;
        const ushortT* kp = &qkv[(size_t)(b * Nn + i0 + r15) * 1536 + 512 + (h << 6) + kq];
        bf16x8 bk0 = *(const bf16x8*)kp;
        bf16x8 bk1 = *(const bf16x8*)(kp + 32);
        f32x4 acc[4];
#pragma unroll
        for (int mt = 0; mt < 4; ++mt) {
            acc[mt] = MFMA16(af[mt][0], bk0, fzero4());
            acc[mt] = MFMA16(af[mt][1], bk1, acc[mt]);
        }
        int ic = i0 + r15;
#pragma unroll
        for (int mt = 0; mt < 4; ++mt)
#pragma unroll
            for (int r = 0; r < 4; ++r) {
                int a = mt * 16 + rbase + r;
                if (a < AG) {
                    float v = acc[mt][r] + b1[(size_t)(h * AG + a) * Nn + ic];
                    L[(size_t)(bh * AG + a) * Nn + ic] = f2bf(v);
                }
            }
    }
}

// ============ softmax over bf16 rows of length Nn ============
__global__ __launch_bounds__(256)
void softmax_rows_bf(ushortT* __restrict__ L) {
    __shared__ float ex[Nn];
    __shared__ float red[256];
    ushortT* p = L + (size_t)blockIdx.x * Nn;
    int t = threadIdx.x;
    float m = -1e30f;
    for (int i = t; i < Nn; i += 256) { float v = bf2f(p[i]); ex[i] = v; m = fmaxf(m, v); }
    red[t] = m; __syncthreads();
    for (int s = 128; s; s >>= 1) { if (t < s) red[t] = fmaxf(red[t], red[t + s]); __syncthreads(); }
    m = red[0]; __syncthreads();
    float sum = 0.f;
    for (int i = t; i < Nn; i += 256) { float e = __expf(ex[i] - m); ex[i] = e; sum += e; }
    red[t] = sum; __syncthreads();
    for (int s = 128; s; s >>= 1) { if (t < s) red[t] += red[t + s]; __syncthreads(); }
    float inv = 1.f / red[0];
    for (int i = t; i < Nn; i += 256) p[i] = f2bf(ex[i] * inv);
}

__global__ void zerof(float* __restrict__ p, int nfl) {
    int g = blockIdx.x * 256 + threadIdx.x;
    if (g < nfl) p[g] = 0.f;
}

// ============ agent_v via MFMA: av[a][d] += P[a][i]·v[i][d], one wave per 64-i chunk ====
// A = P rows (direct global frags from L), B = v via per-wave LDS transpose. grid (13,128)
__global__ __launch_bounds__(256)
void agent_v_mfma(const ushortT* __restrict__ qkv, const ushortT* __restrict__ L,
                  float* __restrict__ av) {
    __shared__ __align__(16) ushortT vt[4][64 * 72];   // per-wave vT[d][i]
    int t = threadIdx.x, lane = t & 63, wid = t >> 6;
    int bh = blockIdx.y, b = bh >> 3, h = bh & 7;
    int sub = blockIdx.x * 4 + wid;
    if (sub >= AG) return;                 // 49 chunks of 64 i
    int i0 = sub * 64;
    ushortT* vtw = vt[wid];
    {
        const ushortT* vp = &qkv[(size_t)(b * Nn + i0 + lane) * 1536 + 1024 + (h << 6)];
#pragma unroll
        for (int d8 = 0; d8 < 64; d8 += 8) {
            ushort4 u0 = *(const ushort4*)(vp + d8);
            ushort4 u1 = *(const ushort4*)(vp + d8 + 4);
            vtw[(d8 + 0) * 72 + lane] = u0.x; vtw[(d8 + 1) * 72 + lane] = u0.y;
            vtw[(d8 + 2) * 72 + lane] = u0.z; vtw[(d8 + 3) * 72 + lane] = u0.w;
            vtw[(d8 + 4) * 72 + lane] = u1.x; vtw[(d8 + 5) * 72 + lane] = u1.y;
            vtw[(d8 + 6) * 72 + lane] = u1.z; vtw[(d8 + 7) * 72 + lane] = u1.w;
        }
    }
    int r15 = lane & 15, kq = (lane >> 4) << 3;
    f32x4 acc[4][4];
#pragma unroll
    for (int i = 0; i < 4; ++i)
#pragma unroll
        for (int j = 0; j < 4; ++j) acc[i][j] = fzero4();
#pragma unroll
    for (int ks = 0; ks < 2; ++ks) {
        bf16x8 afr[4], bfr[4];
#pragma unroll
        for (int mt = 0; mt < 4; ++mt) {
            int a = min(mt * 16 + r15, AG - 1);
            afr[mt] = *(const bf16x8*)&L[(size_t)(bh * AG + a) * Nn + i0 + ks * 32 + kq];
        }
#pragma unroll
        for (int nt = 0; nt < 4; ++nt)
            bfr[nt] = *(const bf16x8*)&vtw[(nt * 16 + r15) * 72 + ks * 32 + kq];
#pragma unroll
        for (int mt = 0; mt < 4; ++mt)
#pragma unroll
            for (int nt = 0; nt < 4; ++nt)
                acc[mt][nt] = MFMA16(afr[mt], bfr[nt], acc[mt][nt]);
    }
    int rbase = (lane >> 4) << 2;
#pragma unroll
    for (int mt = 0; mt < 4; ++mt)
#pragma unroll
        for (int r = 0; r < 4; ++r) {
            int a = mt * 16 + rbase + r;
            if (a < AG) {
#pragma unroll
                for (int nt = 0; nt < 4; ++nt)
                    atomicAdd(&av[((size_t)(bh * AG + a) << 6) + nt * 16 + r15],
                              acc[mt][nt][r]);
            }
        }
}

// ============ fused q-attention via MFMA: QK^T -> reg softmax -> P·av ============
// grid (7, 128); per wave 7 tiles of 16 rows. P LDS round-trip (C-layout -> A-frag).
__global__ __launch_bounds__(256)
void q_attn_mfma(const ushortT* __restrict__ qkv, const float* __restrict__ at,
                 const float* __restrict__ av, const float* __restrict__ b2,
                 ushortT* __restrict__ attn) {
    __shared__ __align__(16) ushortT ah_s[64 * 72];
    __shared__ __align__(16) ushortT avT[64 * 72];
    __shared__ __align__(16) ushortT p_s[4][16 * 72];
    int t = threadIdx.x, lane = t & 63, wid = t >> 6;
    int bh = blockIdx.y, b = bh >> 3, h = bh & 7;
    for (int idx = t; idx < 512; idx += 256) {
        int a = idx >> 3, d8 = (idx & 7) << 3;
        bf16x8 tmp;
        if (a < AG) {
            const float* p = &at[((size_t)(b * AG + a) << 9) + (h << 6) + d8];
#pragma unroll
            for (int j = 0; j < 8; ++j) tmp[j] = (short)f2bf(p[j] * 0.125f);
        } else {
#pragma unroll
            for (int j = 0; j < 8; ++j) tmp[j] = 0;
        }
        *(bf16x8*)&ah_s[a * 72 + d8] = tmp;
    }
    for (int idx = t; idx < 4096; idx += 256) {     // avT[d][a] <- av[a][d]
        int a = idx >> 6, d = idx & 63;
        float v = (a < AG) ? av[((size_t)(bh * AG + a) << 6) + d] : 0.f;
        avT[d * 72 + a] = f2bf(v);
    }
    __syncthreads();
    int r15 = lane & 15, kq = (lane >> 4) << 3;
    bf16x8 bah[4][2], bav[4][2];
#pragma unroll
    for (int nt = 0; nt < 4; ++nt)
#pragma unroll
        for (int ks = 0; ks < 2; ++ks) {
            bah[nt][ks] = *(const bf16x8*)&ah_s[(nt * 16 + r15) * 72 + ks * 32 + kq];
            bav[nt][ks] = *(const bf16x8*)&avT[(nt * 16 + r15) * 72 + ks * 32 + kq];
        }
    ushortT* psw = p_s[wid];
    int i0b = blockIdx.x * 448;
    int rbase = (lane >> 4) << 2;
    for (int tt = 0; tt < 7; ++tt) {
        int i0 = i0b + (wid * 7 + tt) * 16;
        const ushortT* qp = &qkv[(size_t)(b * Nn + i0 + r15) * 1536 + (h << 6) + kq];
        bf16x8 aq0 = *(const bf16x8*)qp;
        bf16x8 aq1 = *(const bf16x8*)(qp + 32);
        f32x4 lg[4];
#pragma unroll
        for (int nt = 0; nt < 4; ++nt) {
            lg[nt] = MFMA16(aq0, bah[nt][0], fzero4());
            lg[nt] = MFMA16(aq1, bah[nt][1], lg[nt]);
        }
        float p4[4][4];   // [nt][r]
#pragma unroll
        for (int r = 0; r < 4; ++r) {
            int i = i0 + rbase + r;
            float vals[4]; float mx = -1e30f;
#pragma unroll
            for (int nt = 0; nt < 4; ++nt) {
                int a = nt * 16 + r15;
                float v = -1e30f;
                if (a < AG) v = lg[nt][r] + b2[(size_t)(h * Nn + i) * AG + a];
                vals[nt] = v;
                mx = fmaxf(mx, v);
            }
#pragma unroll
            for (int off = 8; off >= 1; off >>= 1) mx = fmaxf(mx, __shfl_xor(mx, off));
            float sm = 0.f;
#pragma unroll
            for (int nt = 0; nt < 4; ++nt) {
                float e = (vals[nt] > -1e29f) ? __expf(vals[nt] - mx) : 0.f;
                vals[nt] = e; sm += e;
            }
#pragma unroll
            for (int off = 8; off >= 1; off >>= 1) sm += __shfl_xor(sm, off);
            float inv = 1.f / sm;
#pragma unroll
            for (int nt = 0; nt < 4; ++nt) p4[nt][r] = vals[nt] * inv;
        }
#pragma unroll
        for (int nt = 0; nt < 4; ++nt)
#pragma unroll
            for (int r = 0; r < 4; ++r)
                psw[(rbase + r) * 72 + nt * 16 + r15] = f2bf(p4[nt][r]);
        // same-wave LDS write->read (compiler inserts lgkmcnt wait; p_s is per-wave)
        bf16x8 ap0 = *(const bf16x8*)&psw[r15 * 72 + kq];
        bf16x8 ap1 = *(const bf16x8*)&psw[r15 * 72 + 32 + kq];
        f32x4 ov[4];
#pragma unroll
        for (int nt = 0; nt < 4; ++nt) {
            ov[nt] = MFMA16(ap0, bav[nt][0], fzero4());
            ov[nt] = MFMA16(ap1, bav[nt][1], ov[nt]);
        }
#pragma unroll
        for (int r = 0; r < 4; ++r) {
            int i = i0 + rbase + r;
            ushortT* op = &attn[(size_t)(b * Nn + i) * C_ + (h << 6)];
#pragma unroll
            for (int nt = 0; nt < 4; ++nt)
                op[nt * 16 + r15] = f2bf(ov[nt][r]);
        }
    }
}

// ============ depthwise 3x3 conv on v, added into attn; 8 channels/thread ============
__global__ void dwc_add_v(const ushortT* __restrict__ qkv, const float* __restrict__ wT,
                          const float* __restrict__ bb, ushortT* __restrict__ attn) {
    int g = blockIdx.x * 256 + threadIdx.x;   // B*Nn*64
    int c8 = (g & 63) << 3;
    int bi = g >> 6;
    int i = bi % Nn;
    int y = i / 56, x = i % 56;
    float acc[8];
    {
        float4 b0 = *(const float4*)&bb[c8];
        float4 b1 = *(const float4*)&bb[c8 + 4];
        acc[0] = b0.x; acc[1] = b0.y; acc[2] = b0.z; acc[3] = b0.w;
        acc[4] = b1.x; acc[5] = b1.y; acc[6] = b1.z; acc[7] = b1.w;
    }
#pragma unroll
    for (int dy = -1; dy <= 1; ++dy) {
        int yy = y + dy; if (yy < 0 || yy > 55) continue;
#pragma unroll
        for (int dx = -1; dx <= 1; ++dx) {
            int xx = x + dx; if (xx < 0 || xx > 55) continue;
            const ushortT* vp = &qkv[(size_t)(bi + dy * 56 + dx) * 1536 + 1024 + c8];
            ushort4 u0 = *(const ushort4*)vp;
            ushort4 u1 = *(const ushort4*)(vp + 4);
            const float* wp = &wT[((dy + 1) * 3 + dx + 1) * 512 + c8];
            float4 w0 = *(const float4*)wp;
            float4 w1 = *(const float4*)(wp + 4);
            acc[0] += bf2f(u0.x) * w0.x; acc[1] += bf2f(u0.y) * w0.y;
            acc[2] += bf2f(u0.z) * w0.z; acc[3] += bf2f(u0.w) * w0.w;
            acc[4] += bf2f(u1.x) * w1.x; acc[5] += bf2f(u1.y) * w1.y;
            acc[6] += bf2f(u1.z) * w1.z; acc[7] += bf2f(u1.w) * w1.w;
        }
    }
    ushortT* op = &attn[(size_t)bi * C_ + c8];
    ushort4 a0 = *(const ushort4*)op;
    ushort4 a1 = *(const ushort4*)(op + 4);
    ushort4 o0 = make_ushort4(f2bf(bf2f(a0.x) + acc[0]), f2bf(bf2f(a0.y) + acc[1]),
                              f2bf(bf2f(a0.z) + acc[2]), f2bf(bf2f(a0.w) + acc[3]));
    ushort4 o1 = make_ushort4(f2bf(bf2f(a1.x) + acc[4]), f2bf(bf2f(a1.y) + acc[5]),
                              f2bf(bf2f(a1.z) + acc[6]), f2bf(bf2f(a1.w) + acc[7]));
    *(ushort4*)op = o0; *(ushort4*)(op + 4) = o1;
}

extern "C" void kernel_launch(void* const* d_in, const int* in_sizes, int n_in,
                              void* d_out, int out_size, void* d_ws, size_t ws_size,
                              hipStream_t stream) {
    const float* x      = (const float*)d_in[0];
    const float* q_w    = (const float*)d_in[3];
    const float* kv_w   = (const float*)d_in[4];
    const float* proj_w = (const float*)d_in[5];
    const float* proj_b = (const float*)d_in[6];
    const float* dwc_w  = (const float*)d_in[7];
    const float* dwc_b  = (const float*)d_in[8];
    const float* an_b   = (const float*)d_in[9];
    const float* na_b   = (const float*)d_in[10];
    const float* ah_b   = (const float*)d_in[11];
    const float* aw_b   = (const float*)d_in[12];
    const float* ha_b   = (const float*)d_in[13];
    const float* wa_b   = (const float*)d_in[14];
    float* out = (float*)d_out;

    // ---- workspace (220,682,240 B ≈ 210.5 MiB); R region reused: xb -> L -> attn ----
    char* ws = (char*)d_ws;
    ushortT* R    = (ushortT*)(ws);                 // 51,380,224 B
    ushortT* qkv  = (ushortT*)(ws + 51380224);      // 154,140,672 B
    ushortT* Wqkv = (ushortT*)(ws + 205520896);     // 1,572,864 B
    ushortT* Wp   = (ushortT*)(ws + 207093760);     // 524,288 B
    float*   wT   = (float*)(ws + 207618048);       // 18,432 B
    float*   at   = (float*)(ws + 207636480);       // 1,605,632 B
    float*   b1   = (float*)(ws + 209242112);       // 4,917,248 B
    float*   b2   = (float*)(ws + 214159360);       // 4,917,248 B
    float*   av   = (float*)(ws + 219076608);       // 1,605,632 B
    ushortT* xb   = R;            // 50176x512 bf16 (dead after QKV GEMM)
    ushortT* L    = R;            // 6272x3136  bf16 (dead before attn written)
    ushortT* attn = R;            // 50176x512 bf16

    // 0) dtype conversions / repacks
    cvt_f2b4<<<25088, 256, 0, stream>>>(x, xb, 6422528);
    cvt_f2b4<<<256,   256, 0, stream>>>(q_w, Wqkv, 65536);
    cvt_f2b4<<<512,   256, 0, stream>>>(kv_w, Wqkv + 262144, 131072);
    cvt_f2b4<<<256,   256, 0, stream>>>(proj_w, Wp, 65536);
    repack_w<<<18,    256, 0, stream>>>(dwc_w, wT);
    // 1) fused QKV GEMM (bf16 MFMA)
    gemm_mfma<ushortT><<<dim3(12, 392), 256, 0, stream>>>(xb, Wqkv, nullptr, qkv, 1536, 512);
    // 2) agent tokens
    agent_pool<<<196, 256, 0, stream>>>(qkv, at);
    // 3) position biases
    bias1_k<<<4802, 256, 0, stream>>>(an_b, ah_b, aw_b, b1);
    bias2_k<<<4802, 256, 0, stream>>>(na_b, ha_b, wa_b, b2);
    // 4) agent attention
    agent_logits_mfma<<<dim3(7, 128), 256, 0, stream>>>(qkv, at, b1, L);
    softmax_rows_bf<<<6272, 256, 0, stream>>>(L);
    zerof<<<1568, 256, 0, stream>>>(av, B_ * HEADS * AG * HD);
    agent_v_mfma<<<dim3(13, 128), 256, 0, stream>>>(qkv, L, av);
    // 5) q attention (fused MFMA)
    q_attn_mfma<<<dim3(7, 128), 256, 0, stream>>>(qkv, at, av, b2, attn);
    // 6) depthwise conv add
    dwc_add_v<<<12544, 256, 0, stream>>>(qkv, wT, dwc_b, attn);
    // 7) output projection (bf16 MFMA, fp32 out + bias)
    gemm_mfma<float><<<dim3(4, 392), 256, 0, stream>>>(attn, Wp, proj_b, out, 512, 512);
}